// Round 5
// baseline (299.500 us; speedup 1.0000x reference)
//
#include <hip/hip_runtime.h>
#include <math.h>

namespace {
constexpr int kB    = 32;
constexpr int kMel  = 128;
constexpr int kT    = 8192;
constexpr int kKeys = 88;
constexpr int kTop  = 15;   // top[13] = 14th largest, top[14] = 15th largest
constexpr int kD    = 57;   // distinct mel bins among the 88 keys

constexpr int kThreads = 1024;            // 16 waves, one block per CU
constexpr int kWaves   = kThreads / 64;
constexpr int kBlockT  = kThreads;        // t-span per block (1 t per thread)

typedef float floatx4 __attribute__((ext_vector_type(4)));  // native vector:
// __builtin_nontemporal_store rejects HIP_vector_type<float,4> but takes this.

// key_bins is a DETERMINISTIC function of the mel filterbank geometry (the
// only randomness in setup_inputs feeds mel). Verified per block against the
// real key_bins input; mismatch -> generic fallback. Wrong table costs speed,
// never correctness.
constexpr int kDistM[kD] = {
    1,  2,  3,  4,  5,  6,  7,  8,  9, 10, 11, 12, 13, 14, 15, 16, 17,
   19, 20, 21, 22, 23, 25, 26, 28, 29, 31, 33, 35, 37, 39, 42,
   44, 46, 49, 51, 53, 56, 58, 60, 63, 65, 68, 70, 72, 75, 77, 79,
   82, 84, 86, 89, 91, 93, 96, 98, 101};
constexpr int kCnt[kD] = {
    5, 9, 6, 4, 3, 3, 3, 2, 2, 2, 1, 2, 1, 1, 1, 1, 2,
    1, 1, 1, 1, 1, 1, 1, 1, 1, 1, 1, 1, 1, 1, 1,
    1, 1, 1, 1, 1, 1, 1, 1, 1, 1, 1, 1, 1, 1, 1, 1,
    1, 1, 1, 1, 1, 1, 1, 1, 1};
constexpr int kIdx[kKeys] = {
    0, 0, 0, 0, 0,
    1, 1, 1, 1, 1, 1, 1, 1, 1,
    2, 2, 2, 2, 2, 2,
    3, 3, 3, 3,
    4, 4, 4,
    5, 5, 5,
    6, 6, 6,
    7, 7,
    8, 8,
    9, 9,
   10,
   11, 11,
   12, 13, 14, 15,
   16, 16,
   17, 18, 19, 20, 21, 22, 23, 24, 25, 26, 27, 28, 29, 30, 31,
   32, 33, 34, 35, 36, 37, 38, 39, 40, 41, 42, 43, 44, 45, 46, 47,
   48, 49, 50, 51, 52, 53, 54, 55, 56};
}

__device__ __forceinline__ void top_insert(float (&top)[kTop], float v) {
#pragma unroll
  for (int j = 0; j < kTop; ++j) {
    const float hi = fmaxf(top[j], v);
    v = fminf(top[j], v);
    top[j] = hi;
  }
}

__global__ __launch_bounds__(kThreads, 1) void key_probs_kernel(
    const float* __restrict__ mel, const int* __restrict__ key_bins,
    float* __restrict__ out) {
  __shared__ int sbins[kKeys];
  __shared__ unsigned long long fl[kKeys][kWaves];  // packed flags: bit l of
                                                    // fl[k][w] = flag(t0+64w+l)
  const int tid = threadIdx.x;
  int ok = 1;
  if (tid < kKeys) {
    const int bin = key_bins[tid];
    sbins[tid] = bin;
    ok = (bin == kDistM[kIdx[tid]]);
  }
  const int allok = __syncthreads_and(ok);

  const int t0 = blockIdx.x * kBlockT;
  const int b  = blockIdx.y;
  const float* melb = mel + (size_t)b * kMel * kT + t0 + tid;
  const int w = tid >> 6, lane = tid & 63;

  if (allok) {
    // ===== FAST PATH: compile-time bins, 89 loads, 57 CSE'd sums =====
    float sd[kD];
#pragma unroll
    for (int j = 0; j < kD; ++j) {
      const int m = kDistM[j];
      float v = melb[(size_t)m * kT];
      if (2 * m < kMel) v += melb[(size_t)(2 * m) * kT];
      if (3 * m < kMel) v += melb[(size_t)(3 * m) * kT];
      sd[j] = v;
    }

    // weighted 14th/15th largest (rank on sums; exp is monotone)
    float top[kTop];
#pragma unroll
    for (int j = 0; j < kTop; ++j) top[j] = -1e30f;
#pragma unroll
    for (int j = 0; j < kD; ++j) {
#pragma unroll
      for (int c = 0; c < kCnt[j]; ++c) top_insert(top, sd[j]);
    }

    float r74 = top[13];
    const float vstar = top[13];

    // tie safety: exact ties within ONE duplicated bin are safe (reference
    // products bit-identical, thresh == that product). Ambiguous only if a
    // near-but-not-exact tie, or >=2 DISTINCT bins exactly equal vstar.
    int neq = 0;
    bool near_ne = false;
#pragma unroll
    for (int j = 0; j < kD; ++j) {
      const float d = sd[j] - vstar;
      const bool c = fabsf(d) < 1e-5f;
      near_ne = near_ne || (c && (d != 0.0f));
      neq += (c && (d == 0.0f)) ? 1 : 0;
    }
    const bool amb = near_ne || (neq > 1);

    if (amb) {  // rare: product space with np-compatible exp (exec-masked)
      float tp[kTop];
#pragma unroll
      for (int j = 0; j < kTop; ++j) tp[j] = 0.0f;
#pragma unroll
      for (int j = 0; j < kD; ++j) {
        const int m = kDistM[j];
        float v = (float)::exp((double)melb[(size_t)m * kT]);
        if (2 * m < kMel) v *= (float)::exp((double)melb[(size_t)(2 * m) * kT]);
        if (3 * m < kMel) v *= (float)::exp((double)melb[(size_t)(3 * m) * kT]);
        sd[j] = v;
#pragma unroll
        for (int c = 0; c < kCnt[j]; ++c) top_insert(tp, v);
      }
      r74 = tp[13];
    }

    // flags -> packed LDS bitmask via ballot (whole wave, uniform path)
#pragma unroll
    for (int k = 0; k < kKeys; ++k) {
      const unsigned long long m = __ballot(sd[kIdx[k]] >= r74);
      if (lane == 0) fl[k][w] = m;
    }
  } else {
    // ===== GENERIC FALLBACK: data-driven bins (proven R2 path) =====
    float s[kKeys];
#pragma unroll
    for (int k = 0; k < kKeys; ++k) {
      const int m = __builtin_amdgcn_readfirstlane(sbins[k]);
      const int r1 = (m < 64) ? 2 * m : m;
      const int r2 = (m < 43) ? 3 * m : m;
      const float w1 = (m < 64) ? 1.0f : 0.0f;
      const float w2 = (m < 43) ? 1.0f : 0.0f;
      const float v0 = melb[(size_t)m * kT];
      const float v1 = melb[(size_t)r1 * kT];
      const float v2 = melb[(size_t)r2 * kT];
      s[k] = v0 + w1 * v1 + w2 * v2;
    }

    float top[kTop];
#pragma unroll
    for (int j = 0; j < kTop; ++j) top[j] = -1e30f;
#pragma unroll
    for (int k = 0; k < kKeys; ++k) top_insert(top, s[k]);

    float r74 = top[13];
    const float vstar = top[13];

    bool tieok = true;
    int bmin = 0x3fffffff;
    int bmax = -0x3fffffff;
#pragma unroll
    for (int k = 0; k < kKeys; ++k) {
      const int m = __builtin_amdgcn_readfirstlane(sbins[k]);
      const float d = s[k] - vstar;
      const bool c = fabsf(d) < 1e-5f;
      tieok = tieok && (!c || (d == 0.0f));
      bmin = (c && m < bmin) ? m : bmin;
      bmax = (c && m > bmax) ? m : bmax;
    }
    const bool amb = !(tieok && (bmin == bmax));

    if (amb) {
      float tp[kTop];
#pragma unroll
      for (int j = 0; j < kTop; ++j) tp[j] = 0.0f;
#pragma unroll
      for (int k = 0; k < kKeys; ++k) {
        const int m = __builtin_amdgcn_readfirstlane(sbins[k]);
        float v = (float)::exp((double)melb[(size_t)m * kT]);
        if (m < 64) v *= (float)::exp((double)melb[(size_t)(2 * m) * kT]);
        if (m < 43) v *= (float)::exp((double)melb[(size_t)(3 * m) * kT]);
        s[k] = v;
        top_insert(tp, v);
      }
      r74 = tp[13];
    }

#pragma unroll
    for (int k = 0; k < kKeys; ++k) {
      const unsigned long long m = __ballot(s[k] >= r74);
      if (lane == 0) fl[k][w] = m;
    }
  }

  __syncthreads();

  // ===== cooperative write-out: 176 rows x 4KB contiguous per block =====
  // Each wave owns 11 rows; each store instr = 64 lanes x float4 = 1KB.
  // This replaces 176 scalar stores/thread (256B slivers at 32KB stride,
  // which pinned effective HBM write BW at ~1.4 TB/s in R0-R3).
  float* ob = out + (size_t)b * kKeys * kT + t0;
  const size_t copyStride = (size_t)kB * kKeys * kT;
#pragma unroll
  for (int rr = 0; rr < 11; ++rr) {
    const int r = w * 11 + rr;                 // 16 waves * 11 = 176 rows
    const int k = (r < kKeys) ? r : r - kKeys;
    float* dst = ob + ((r < kKeys) ? 0 : copyStride) + (size_t)k * kT;
#pragma unroll
    for (int i = 0; i < 4; ++i) {
      const unsigned long long word = fl[k][i * 4 + (lane >> 4)];
      const int sh = (lane & 15) * 4;
      const unsigned bits = (unsigned)(word >> sh) & 0xFu;
      floatx4 v;
      v.x = (bits & 1u) ? 1.0f : 0.0f;
      v.y = (bits & 2u) ? 1.0f : 0.0f;
      v.z = (bits & 4u) ? 1.0f : 0.0f;
      v.w = (bits & 8u) ? 1.0f : 0.0f;
      __builtin_nontemporal_store(v, (floatx4*)(dst + i * 256 + lane * 4));
    }
  }
}

extern "C" void kernel_launch(void* const* d_in, const int* in_sizes, int n_in,
                              void* d_out, int out_size, void* d_ws, size_t ws_size,
                              hipStream_t stream) {
  const float* mel = (const float*)d_in[0];
  const int* key_bins = (const int*)d_in[1];
  float* out = (float*)d_out;
  dim3 grid(kT / kBlockT, kB);
  key_probs_kernel<<<grid, dim3(kThreads), 0, stream>>>(mel, key_bins, out);
}

// Round 6
// 282.463 us; speedup vs baseline: 1.0603x; 1.0603x over previous
//
#include <hip/hip_runtime.h>
#include <math.h>

namespace {
constexpr int kB    = 32;
constexpr int kMel  = 128;
constexpr int kT    = 8192;
constexpr int kKeys = 88;
constexpr int kTop  = 15;   // top[13] = 14th largest, top[14] = 15th largest
constexpr int kD    = 57;   // distinct mel bins among the 88 keys

constexpr int kThreads = 512;             // 8 waves; grid 512 -> 2 blocks/CU so
constexpr int kWaves   = kThreads / 64;   // one block's gather/sort overlaps the
constexpr int kBlockT  = kThreads;        // other's store drain (R5 had 1/CU,
                                          // fully serial phases).

typedef float floatx4 __attribute__((ext_vector_type(4)));  // native vector:
// __builtin_nontemporal_store rejects HIP_vector_type<float,4> but takes this.

// key_bins is a DETERMINISTIC function of the mel filterbank geometry (the
// only randomness in setup_inputs feeds mel). Verified per block against the
// real key_bins input; mismatch -> generic fallback. Wrong table costs speed,
// never correctness.
constexpr int kDistM[kD] = {
    1,  2,  3,  4,  5,  6,  7,  8,  9, 10, 11, 12, 13, 14, 15, 16, 17,
   19, 20, 21, 22, 23, 25, 26, 28, 29, 31, 33, 35, 37, 39, 42,
   44, 46, 49, 51, 53, 56, 58, 60, 63, 65, 68, 70, 72, 75, 77, 79,
   82, 84, 86, 89, 91, 93, 96, 98, 101};
constexpr int kCnt[kD] = {
    5, 9, 6, 4, 3, 3, 3, 2, 2, 2, 1, 2, 1, 1, 1, 1, 2,
    1, 1, 1, 1, 1, 1, 1, 1, 1, 1, 1, 1, 1, 1, 1,
    1, 1, 1, 1, 1, 1, 1, 1, 1, 1, 1, 1, 1, 1, 1, 1,
    1, 1, 1, 1, 1, 1, 1, 1, 1};
constexpr int kIdx[kKeys] = {
    0, 0, 0, 0, 0,
    1, 1, 1, 1, 1, 1, 1, 1, 1,
    2, 2, 2, 2, 2, 2,
    3, 3, 3, 3,
    4, 4, 4,
    5, 5, 5,
    6, 6, 6,
    7, 7,
    8, 8,
    9, 9,
   10,
   11, 11,
   12, 13, 14, 15,
   16, 16,
   17, 18, 19, 20, 21, 22, 23, 24, 25, 26, 27, 28, 29, 30, 31,
   32, 33, 34, 35, 36, 37, 38, 39, 40, 41, 42, 43, 44, 45, 46, 47,
   48, 49, 50, 51, 52, 53, 54, 55, 56};
}

__device__ __forceinline__ void top_insert(float (&top)[kTop], float v) {
#pragma unroll
  for (int j = 0; j < kTop; ++j) {
    const float hi = fmaxf(top[j], v);
    v = fminf(top[j], v);
    top[j] = hi;
  }
}

__global__ __launch_bounds__(kThreads, 2) void key_probs_kernel(
    const float* __restrict__ mel, const int* __restrict__ key_bins,
    float* __restrict__ out) {
  __shared__ int sbins[kKeys];
  __shared__ unsigned long long fl[kKeys][kWaves];  // packed flags: bit l of
                                                    // fl[k][w] = flag(t0+64w+l)
  const int tid = threadIdx.x;
  int ok = 1;
  if (tid < kKeys) {
    const int bin = key_bins[tid];
    sbins[tid] = bin;
    ok = (bin == kDistM[kIdx[tid]]);
  }
  const int allok = __syncthreads_and(ok);

  const int t0 = blockIdx.x * kBlockT;
  const int b  = blockIdx.y;
  const float* melb = mel + (size_t)b * kMel * kT + t0 + tid;
  const int w = tid >> 6, lane = tid & 63;

  if (allok) {
    // ===== FAST PATH: compile-time bins, 89 loads, 57 CSE'd sums =====
    // Load+sum+insert fused per j so the top-15 network's VALU overlaps
    // outstanding loads instead of running after them.
    float sd[kD];
    float top[kTop];
#pragma unroll
    for (int j = 0; j < kTop; ++j) top[j] = -1e30f;  // sums can be negative
#pragma unroll
    for (int j = 0; j < kD; ++j) {
      const int m = kDistM[j];
      float v = melb[(size_t)m * kT];
      if (2 * m < kMel) v += melb[(size_t)(2 * m) * kT];
      if (3 * m < kMel) v += melb[(size_t)(3 * m) * kT];
      sd[j] = v;
      // weighted insert: each distinct value counts kCnt[j] times
#pragma unroll
      for (int c = 0; c < kCnt[j]; ++c) top_insert(top, v);
    }

    float r74 = top[13];
    const float vstar = top[13];

    // tie safety: exact ties within ONE duplicated bin are safe (reference
    // products bit-identical, thresh == that product). Ambiguous only if a
    // near-but-not-exact tie, or >=2 DISTINCT bins exactly equal vstar.
    int neq = 0;
    bool near_ne = false;
#pragma unroll
    for (int j = 0; j < kD; ++j) {
      const float d = sd[j] - vstar;
      const bool c = fabsf(d) < 1e-5f;
      near_ne = near_ne || (c && (d != 0.0f));
      neq += (c && (d == 0.0f)) ? 1 : 0;
    }
    const bool amb = near_ne || (neq > 1);

    if (amb) {  // rare: product space with np-compatible exp (exec-masked)
      float tp[kTop];
#pragma unroll
      for (int j = 0; j < kTop; ++j) tp[j] = 0.0f;
#pragma unroll
      for (int j = 0; j < kD; ++j) {
        const int m = kDistM[j];
        float v = (float)::exp((double)melb[(size_t)m * kT]);
        if (2 * m < kMel) v *= (float)::exp((double)melb[(size_t)(2 * m) * kT]);
        if (3 * m < kMel) v *= (float)::exp((double)melb[(size_t)(3 * m) * kT]);
        sd[j] = v;
#pragma unroll
        for (int c = 0; c < kCnt[j]; ++c) top_insert(tp, v);
      }
      r74 = tp[13];
    }

    // flags -> packed LDS bitmask via ballot (whole wave, uniform path)
#pragma unroll
    for (int k = 0; k < kKeys; ++k) {
      const unsigned long long m = __ballot(sd[kIdx[k]] >= r74);
      if (lane == 0) fl[k][w] = m;
    }
  } else {
    // ===== GENERIC FALLBACK: data-driven bins (proven R2 path) =====
    float s[kKeys];
#pragma unroll
    for (int k = 0; k < kKeys; ++k) {
      const int m = __builtin_amdgcn_readfirstlane(sbins[k]);
      const int r1 = (m < 64) ? 2 * m : m;
      const int r2 = (m < 43) ? 3 * m : m;
      const float w1 = (m < 64) ? 1.0f : 0.0f;
      const float w2 = (m < 43) ? 1.0f : 0.0f;
      const float v0 = melb[(size_t)m * kT];
      const float v1 = melb[(size_t)r1 * kT];
      const float v2 = melb[(size_t)r2 * kT];
      s[k] = v0 + w1 * v1 + w2 * v2;
    }

    float top[kTop];
#pragma unroll
    for (int j = 0; j < kTop; ++j) top[j] = -1e30f;
#pragma unroll
    for (int k = 0; k < kKeys; ++k) top_insert(top, s[k]);

    float r74 = top[13];
    const float vstar = top[13];

    bool tieok = true;
    int bmin = 0x3fffffff;
    int bmax = -0x3fffffff;
#pragma unroll
    for (int k = 0; k < kKeys; ++k) {
      const int m = __builtin_amdgcn_readfirstlane(sbins[k]);
      const float d = s[k] - vstar;
      const bool c = fabsf(d) < 1e-5f;
      tieok = tieok && (!c || (d == 0.0f));
      bmin = (c && m < bmin) ? m : bmin;
      bmax = (c && m > bmax) ? m : bmax;
    }
    const bool amb = !(tieok && (bmin == bmax));

    if (amb) {
      float tp[kTop];
#pragma unroll
      for (int j = 0; j < kTop; ++j) tp[j] = 0.0f;
#pragma unroll
      for (int k = 0; k < kKeys; ++k) {
        const int m = __builtin_amdgcn_readfirstlane(sbins[k]);
        float v = (float)::exp((double)melb[(size_t)m * kT]);
        if (m < 64) v *= (float)::exp((double)melb[(size_t)(2 * m) * kT]);
        if (m < 43) v *= (float)::exp((double)melb[(size_t)(3 * m) * kT]);
        s[k] = v;
        top_insert(tp, v);
      }
      r74 = tp[13];
    }

#pragma unroll
    for (int k = 0; k < kKeys; ++k) {
      const unsigned long long m = __ballot(s[k] >= r74);
      if (lane == 0) fl[k][w] = m;
    }
  }

  __syncthreads();

  // ===== cooperative write-out: 176 rows x 2KB contiguous per block =====
  // Each wave owns 22 rows; each store instr = 64 lanes x float4 = 1KB.
  // (R0-R3 wrote 256B slivers at 32KB stride -> ~1.4 TB/s effective; R5's
  // 4KB bursts fixed that but with 1 block/CU the phases were serial.)
  float* ob = out + (size_t)b * kKeys * kT + t0;
  const size_t copyStride = (size_t)kB * kKeys * kT;
#pragma unroll
  for (int rr = 0; rr < 22; ++rr) {
    const int r = w * 22 + rr;                 // 8 waves * 22 = 176 rows
    const int k = (r < kKeys) ? r : r - kKeys;
    float* dst = ob + ((r < kKeys) ? 0 : copyStride) + (size_t)k * kT;
#pragma unroll
    for (int i = 0; i < 2; ++i) {
      const unsigned long long word = fl[k][i * 4 + (lane >> 4)];
      const int sh = (lane & 15) * 4;
      const unsigned bits = (unsigned)(word >> sh) & 0xFu;
      floatx4 v;
      v.x = (bits & 1u) ? 1.0f : 0.0f;
      v.y = (bits & 2u) ? 1.0f : 0.0f;
      v.z = (bits & 4u) ? 1.0f : 0.0f;
      v.w = (bits & 8u) ? 1.0f : 0.0f;
      __builtin_nontemporal_store(v, (floatx4*)(dst + i * 256 + lane * 4));
    }
  }
}

extern "C" void kernel_launch(void* const* d_in, const int* in_sizes, int n_in,
                              void* d_out, int out_size, void* d_ws, size_t ws_size,
                              hipStream_t stream) {
  const float* mel = (const float*)d_in[0];
  const int* key_bins = (const int*)d_in[1];
  float* out = (float*)d_out;
  dim3 grid(kT / kBlockT, kB);
  key_probs_kernel<<<grid, dim3(kThreads), 0, stream>>>(mel, key_bins, out);
}